// Round 8
// baseline (464.362 us; speedup 1.0000x reference)
//
#include <hip/hip_runtime.h>
#include <hip/hip_bf16.h>

typedef __attribute__((ext_vector_type(8))) short short8;
typedef __attribute__((ext_vector_type(4))) float f32x4;

#define NEDGES 800000
#define BM 32
#define NTILES (NEDGES / BM)   // 25000
#define CAT 384
#define APAD 8
#define STRIDE (CAT + APAD)
#define GRIDSZ 512             // 2 persistent 8-wave blocks per CU -> 16 waves/CU

__device__ __forceinline__ unsigned short f2bf(float f) {
  union { float f; unsigned u; } v; v.f = f;
  unsigned r = v.u + 0x7fffu + ((v.u >> 16) & 1u);
  return (unsigned short)(r >> 16);
}

__device__ __forceinline__ float bf2f(unsigned short u) {
  union { unsigned u; float f; } v; v.u = ((unsigned)u) << 16;
  return v.f;
}

// ---------------- prep kernels ----------------

__global__ void prep_w(const float* __restrict__ W1, const float* __restrict__ gamma,
                       const float* __restrict__ W2,
                       unsigned short* __restrict__ Wgt, unsigned short* __restrict__ W2t) {
  int idx = blockIdx.x * 256 + threadIdx.x;
  if (idx < 128 * 384) {
    int n = idx / 384, k = idx % 384;
    Wgt[idx] = f2bf(gamma[k] * W1[k * 128 + n]);
  }
  if (idx < 128 * 128) {
    int n = idx / 128, k = idx % 128;
    W2t[idx] = f2bf(W2[k * 128 + n]);
  }
}

__global__ void prep_gc(const float* __restrict__ W1, const float* __restrict__ gamma,
                        const float* __restrict__ beta, const float* __restrict__ b1,
                        float* __restrict__ G, float* __restrict__ C1) {
  int n = threadIdx.x;  // 128 threads
  float g = 0.f, b = 0.f;
  for (int k = 0; k < 384; ++k) {
    float w = W1[k * 128 + n];
    g = fmaf(gamma[k], w, g);
    b = fmaf(beta[k], w, b);
  }
  G[n] = g;
  C1[n] = b + b1[n];
}

// ---------------- fused persistent pipelined kernel (8-wave blocks) ----------------
// 512 persistent blocks of 512 threads (2/CU -> 16 waves/CU, 4/SIMD at
// VGPR=128). Each wave owns 16 output features (n0 = wave*16). Both GEMMs
// use SWAPPED operands: D[row]=feature, D[col]=edge, so epi1 writes ushort4
// and epi2 stores float4. Weights are register-resident (B1 48 + B2 16
// VGPR) -> zero global loads inside the GEMM phases, keeping the next
// tile's gather loads in flight across the whole pipeline (vmcnt in-order).
// NOTE (R6 lesson): the launch_bounds cap must leave room for the weight
// arrays or the compiler rematerializes them as in-loop global loads
// (signature: FETCH_SIZE 573MB -> 1.67GB). Cap here = 512/4*... = 128 VGPR,
// estimated need ~120.
__global__ __launch_bounds__(512, 4) void edge_fused(
    const float* __restrict__ node_feat,
    const int* __restrict__ esrc,
    const int* __restrict__ edst,
    const float* __restrict__ eptr,
    const unsigned short* __restrict__ Wgt,
    const unsigned short* __restrict__ W2t,
    const float* __restrict__ Gv,
    const float* __restrict__ C1v,
    const float* __restrict__ b2v,
    float* __restrict__ out) {
  __shared__ unsigned short Abuf[2][BM][STRIDE];   // 2 x 32 x 392 x 2B = 50176 B
  __shared__ float muS[2][BM];
  __shared__ float rsS[2][BM];

  const int tid = threadIdx.x;
  const int r  = tid >> 4;      // gather row 0..31
  const int tt = tid & 15;      // 16 threads per row
  const int l  = tid & 63;
  const int wv = tid >> 6;      // wave 0..7 owns features [16wv, 16wv+16)
  const int lr = l & 15;
  const int lkrow = l >> 4;
  const int lk = lkrow * 8;
  const int n0 = wv * 16;

  // ---- loop-invariant weights & constants -> registers ----
  short8 B1[12];   // GEMM1 A-frags (swapped): Wg[feature n0+lr][k-slice]
  short8 B2[4];    // GEMM2 A-frags (swapped): W2[feature n0+lr][k-slice]
#pragma unroll
  for (int ks = 0; ks < 12; ++ks)
    B1[ks] = *(const short8*)&Wgt[(size_t)(n0 + lr) * CAT + ks * 32 + lk];
#pragma unroll
  for (int ks = 0; ks < 4; ++ks)
    B2[ks] = *(const short8*)&W2t[(size_t)(n0 + lr) * 128 + ks * 32 + lk];
  const float4 Gq  = *(const float4*)&Gv[n0 + lkrow * 4];
  const float4 C1q = *(const float4*)&C1v[n0 + lkrow * 4];
  const float4 b2q = *(const float4*)&b2v[n0 + lkrow * 4];

  float4 ev[2], xi[2], xj[2];
  int siP, diP;   // prefetched indices for the NEXT tile to be gathered

  // ---- staging helper (regs -> bf16 LDS + LN stats) ----
  auto stage = [&](int q) {
    float sum = 0.f, sq = 0.f;
#pragma unroll
    for (int i = 0; i < 2; ++i) {
      float4 v = ev[i];
      sum += (v.x + v.y) + (v.z + v.w);
      sq = fmaf(v.x, v.x, sq); sq = fmaf(v.y, v.y, sq);
      sq = fmaf(v.z, v.z, sq); sq = fmaf(v.w, v.w, sq);
      ushort4 pk; pk.x = f2bf(v.x); pk.y = f2bf(v.y); pk.z = f2bf(v.z); pk.w = f2bf(v.w);
      *(ushort4*)&Abuf[q][r][256 + (tt + 16 * i) * 4] = pk;
    }
#pragma unroll
    for (int i = 0; i < 2; ++i) {
      float4 v = xi[i];
      sum += (v.x + v.y) + (v.z + v.w);
      sq = fmaf(v.x, v.x, sq); sq = fmaf(v.y, v.y, sq);
      sq = fmaf(v.z, v.z, sq); sq = fmaf(v.w, v.w, sq);
      ushort4 pk; pk.x = f2bf(v.x); pk.y = f2bf(v.y); pk.z = f2bf(v.z); pk.w = f2bf(v.w);
      *(ushort4*)&Abuf[q][r][0 + (tt + 16 * i) * 4] = pk;
    }
#pragma unroll
    for (int i = 0; i < 2; ++i) {
      float4 v = xj[i];
      sum += (v.x + v.y) + (v.z + v.w);
      sq = fmaf(v.x, v.x, sq); sq = fmaf(v.y, v.y, sq);
      sq = fmaf(v.z, v.z, sq); sq = fmaf(v.w, v.w, sq);
      ushort4 pk; pk.x = f2bf(v.x); pk.y = f2bf(v.y); pk.z = f2bf(v.z); pk.w = f2bf(v.w);
      *(ushort4*)&Abuf[q][r][128 + (tt + 16 * i) * 4] = pk;
    }
    // 16-lane butterfly within the row group
    sum += __shfl_xor(sum, 1); sum += __shfl_xor(sum, 2);
    sum += __shfl_xor(sum, 4); sum += __shfl_xor(sum, 8);
    sq  += __shfl_xor(sq, 1);  sq  += __shfl_xor(sq, 2);
    sq  += __shfl_xor(sq, 4);  sq  += __shfl_xor(sq, 8);
    const float mu = sum * (1.f / 384.f);
    const float var = fmaf(-mu, mu, sq * (1.f / 384.f));
    const float rstd = rsqrtf(var + 1e-5f);
    if (tt == 0) { muS[q][r] = mu; rsS[q][r] = rstd; }
  };

  auto gather = [&](int tl) {  // issue 6 float4 loads for tile tl (uses siP/diP)
    const size_t g = (size_t)tl * BM + r;
    const float4* __restrict__ pe = (const float4*)(eptr + g * 128);
    const float4* __restrict__ pi = (const float4*)(node_feat + (size_t)siP * 128);
    const float4* __restrict__ pj = (const float4*)(node_feat + (size_t)diP * 128);
    ev[0] = pe[tt]; ev[1] = pe[tt + 16];
    xi[0] = pi[tt]; xi[1] = pi[tt + 16];
    xj[0] = pj[tt]; xj[1] = pj[tt + 16];
  };

  // ---- prologue: tile0 gathered+staged; tile1 gather in flight ----
  int tile = blockIdx.x;
  {
    const size_t g0 = (size_t)tile * BM + r;
    siP = esrc[g0]; diP = edst[g0];
    gather(tile);
  }
  int tnext = tile + GRIDSZ;
  if (tnext < NTILES) {
    const size_t g1 = (size_t)tnext * BM + r;
    siP = esrc[g1]; diP = edst[g1];
  }
  stage(0);
  if (tnext < NTILES) {
    gather(tnext);
    const int t3 = tnext + GRIDSZ;
    if (t3 < NTILES) {
      const size_t g3 = (size_t)t3 * BM + r;
      siP = esrc[g3]; diP = edst[g3];
    }
  }
  __syncthreads();

  int p = 0;
  for (;;) {
    // ---------- GEMM1 (swapped; zero global loads) ----------
    f32x4 acc[2];
    acc[0] = (f32x4){0.f, 0.f, 0.f, 0.f};
    acc[1] = (f32x4){0.f, 0.f, 0.f, 0.f};
#pragma unroll
    for (int ks = 0; ks < 12; ++ks) {
      short8 af0 = *(const short8*)&Abuf[p][lr][ks * 32 + lk];
      short8 af1 = *(const short8*)&Abuf[p][16 + lr][ks * 32 + lk];
      acc[0] = __builtin_amdgcn_mfma_f32_16x16x32_bf16(B1[ks], af0, acc[0], 0, 0, 0);
      acc[1] = __builtin_amdgcn_mfma_f32_16x16x32_bf16(B1[ks], af1, acc[1], 0, 0, 0);
    }
    __syncthreads();   // all waves done reading buf[p] x-sections

    // epi1: folded LN + bias + LeakyReLU -> h1 (one ushort4 write per mf)
    // lane holds features n0+lkrow*4+{0..3} of edge lr+16mf
#pragma unroll
    for (int mf = 0; mf < 2; ++mf) {
      const int m = lr + 16 * mf;
      const float mu = muS[p][m];
      const float rs = rsS[p][m];
      float h0 = fmaf(rs, acc[mf][0] - mu * Gq.x, C1q.x);
      float h1 = fmaf(rs, acc[mf][1] - mu * Gq.y, C1q.y);
      float h2 = fmaf(rs, acc[mf][2] - mu * Gq.z, C1q.z);
      float h3 = fmaf(rs, acc[mf][3] - mu * Gq.w, C1q.w);
      h0 = (h0 >= 0.f) ? h0 : 0.01f * h0;
      h1 = (h1 >= 0.f) ? h1 : 0.01f * h1;
      h2 = (h2 >= 0.f) ? h2 : 0.01f * h2;
      h3 = (h3 >= 0.f) ? h3 : 0.01f * h3;
      ushort4 pk; pk.x = f2bf(h0); pk.y = f2bf(h1); pk.z = f2bf(h2); pk.w = f2bf(h3);
      *(ushort4*)&Abuf[p][m][n0 + lkrow * 4] = pk;
    }
    __syncthreads();

    // ---------- GEMM2 (swapped; zero global loads) ----------
    f32x4 acc2[2];
    acc2[0] = (f32x4){0.f, 0.f, 0.f, 0.f};
    acc2[1] = (f32x4){0.f, 0.f, 0.f, 0.f};
#pragma unroll
    for (int ks = 0; ks < 4; ++ks) {
      short8 h0 = *(const short8*)&Abuf[p][lr][ks * 32 + lk];
      short8 h1 = *(const short8*)&Abuf[p][16 + lr][ks * 32 + lk];
      acc2[0] = __builtin_amdgcn_mfma_f32_16x16x32_bf16(B2[ks], h0, acc2[0], 0, 0, 0);
      acc2[1] = __builtin_amdgcn_mfma_f32_16x16x32_bf16(B2[ks], h1, acc2[1], 0, 0, 0);
    }

    // epi2: out = e(bf16, LDS) + h2 + b2  (one float4 store per mf)
    const size_t base = (size_t)tile * BM * 128;
    const int nb = n0 + lkrow * 4;
#pragma unroll
    for (int mf = 0; mf < 2; ++mf) {
      const int m = lr + 16 * mf;
      ushort4 e4 = *(const ushort4*)&Abuf[p][m][256 + nb];
      float4 o;
      o.x = bf2f(e4.x) + acc2[mf][0] + b2q.x;
      o.y = bf2f(e4.y) + acc2[mf][1] + b2q.y;
      o.z = bf2f(e4.z) + acc2[mf][2] + b2q.z;
      o.w = bf2f(e4.w) + acc2[mf][3] + b2q.w;
      *(float4*)&out[base + (size_t)m * 128 + nb] = o;
    }

    if (tnext >= NTILES) break;

    // stage tnext's regs -> buf[p^1] (gathers were issued a full iter ago)
    stage(p ^ 1);

    // issue gathers for t3 = tnext+GRIDSZ, prefetch idx for t4
    const int t3 = tnext + GRIDSZ;
    if (t3 < NTILES) {
      gather(t3);
      const int t4 = t3 + GRIDSZ;
      if (t4 < NTILES) {
        const size_t g4 = (size_t)t4 * BM + r;
        siP = esrc[g4]; diP = edst[g4];
      }
    }
    __syncthreads();
    p ^= 1;
    tile = tnext;
    tnext = t3;
  }
}

extern "C" void kernel_launch(void* const* d_in, const int* in_sizes, int n_in,
                              void* d_out, int out_size, void* d_ws, size_t ws_size,
                              hipStream_t stream) {
  const float* node_feat = (const float*)d_in[0];
  const int* esrc        = (const int*)d_in[1];
  const int* edst        = (const int*)d_in[2];
  const float* e         = (const float*)d_in[3];
  const float* gamma     = (const float*)d_in[4];
  const float* beta      = (const float*)d_in[5];
  const float* W1        = (const float*)d_in[6];
  const float* b1        = (const float*)d_in[7];
  const float* W2        = (const float*)d_in[8];
  const float* b2        = (const float*)d_in[9];
  float* out = (float*)d_out;

  unsigned short* Wgt = (unsigned short*)d_ws;        // 128*384 bf16
  unsigned short* W2t = Wgt + 128 * 384;              // 128*128 bf16
  float* G  = (float*)(W2t + 128 * 128);
  float* C1 = G + 128;

  prep_w<<<192, 256, 0, stream>>>(W1, gamma, W2, Wgt, W2t);
  prep_gc<<<1, 128, 0, stream>>>(W1, gamma, beta, b1, G, C1);

  edge_fused<<<GRIDSZ, 512, 0, stream>>>(node_feat, esrc, edst, e,
                                         Wgt, W2t, G, C1, b2, out);
}

// Round 9
// 349.842 us; speedup vs baseline: 1.3273x; 1.3273x over previous
//
#include <hip/hip_runtime.h>
#include <hip/hip_bf16.h>

typedef __attribute__((ext_vector_type(8))) short short8;
typedef __attribute__((ext_vector_type(4))) float f32x4;

#define NEDGES 800000
#define BM 32
#define NTILES (NEDGES / BM)   // 25000
#define CAT 384
#define APAD 6                 // stride 390 shorts = 195 dwords -> conflict-free b128 frag reads
#define STRIDE (CAT + APAD)
#define GRIDSZ 512             // 2 persistent blocks per CU (proven R5 config)

__device__ __forceinline__ unsigned short f2bf(float f) {
  union { float f; unsigned u; } v; v.f = f;
  unsigned r = v.u + 0x7fffu + ((v.u >> 16) & 1u);
  return (unsigned short)(r >> 16);
}

__device__ __forceinline__ float bf2f(unsigned short u) {
  union { unsigned u; float f; } v; v.u = ((unsigned)u) << 16;
  return v.f;
}

// ---------------- prep kernels ----------------

__global__ void prep_w(const float* __restrict__ W1, const float* __restrict__ gamma,
                       const float* __restrict__ W2,
                       unsigned short* __restrict__ Wgt, unsigned short* __restrict__ W2t) {
  int idx = blockIdx.x * 256 + threadIdx.x;
  if (idx < 128 * 384) {
    int n = idx / 384, k = idx % 384;
    Wgt[idx] = f2bf(gamma[k] * W1[k * 128 + n]);
  }
  if (idx < 128 * 128) {
    int n = idx / 128, k = idx % 128;
    W2t[idx] = f2bf(W2[k * 128 + n]);
  }
}

__global__ void prep_gc(const float* __restrict__ W1, const float* __restrict__ gamma,
                        const float* __restrict__ beta, const float* __restrict__ b1,
                        float* __restrict__ G, float* __restrict__ C1) {
  int n = threadIdx.x;  // 128 threads
  float g = 0.f, b = 0.f;
  for (int k = 0; k < 384; ++k) {
    float w = W1[k * 128 + n];
    g = fmaf(gamma[k], w, g);
    b = fmaf(beta[k], w, b);
  }
  G[n] = g;
  C1[n] = b + b1[n];
}

// ---------------- fused persistent pipelined kernel ----------------
// R5 structure (256 thr, 2 blocks/CU, persistent, double-buffered LDS,
// register-resident weights, zero global loads in GEMM phases).
// R9 deltas: APAD=6 (conflict-free ds_read_b128 frag reads) and SWAPPED
// GEMM1 (D=[feature][edge]) so epi1 writes ushort4 instead of 16 scalar
// ds_write_b16 -> big cut in LDS-pipe pressure (the measured wall).
// NOTE (R6/R8 lesson): keep __launch_bounds__(256,2). Any tighter VGPR cap
// (or 512-thread blocks) makes the compiler rematerialize the weight
// arrays as in-loop global loads (signature: FETCH 573MB -> 1+GB).
__global__ __launch_bounds__(256, 2) void edge_fused(
    const float* __restrict__ node_feat,
    const int* __restrict__ esrc,
    const int* __restrict__ edst,
    const float* __restrict__ eptr,
    const unsigned short* __restrict__ Wgt,
    const unsigned short* __restrict__ W2t,
    const float* __restrict__ Gv,
    const float* __restrict__ C1v,
    const float* __restrict__ b2v,
    float* __restrict__ out) {
  __shared__ unsigned short Abuf[2][BM][STRIDE];   // 2 x 32 x 390 x 2B = 49920 B
  __shared__ float muS[2][BM];
  __shared__ float rsS[2][BM];

  const int tid = threadIdx.x;
  const int r  = tid >> 3;      // gather row 0..31
  const int tt = tid & 7;       // 8 threads per row
  const int l = tid & 63;
  const int w = tid >> 6;       // wave 0..3 owns n-cols [32w,32w+32)
  const int lr = l & 15;
  const int lkrow = l >> 4;
  const int lk = lkrow * 8;
  const int n0 = w * 32;

  // ---- loop-invariant weights & constants -> registers ----
  short8 B1[2][12];   // GEMM1 A-frags (swapped): Wg[feature n0+nf*16+lr][k]
  short8 B2[2][4];    // GEMM2 A-frags (swapped): W2[feature][k]
  float4 Gq[2], C1q[2], b2q[2];
#pragma unroll
  for (int nf = 0; nf < 2; ++nf) {
    const int n = n0 + nf * 16 + lr;
    const int nb = n0 + nf * 16 + lkrow * 4;
    Gq[nf]  = *(const float4*)&Gv[nb];
    C1q[nf] = *(const float4*)&C1v[nb];
    b2q[nf] = *(const float4*)&b2v[nb];
#pragma unroll
    for (int ks = 0; ks < 12; ++ks)
      B1[nf][ks] = *(const short8*)&Wgt[(size_t)n * CAT + ks * 32 + lk];
#pragma unroll
    for (int ks = 0; ks < 4; ++ks)
      B2[nf][ks] = *(const short8*)&W2t[(size_t)n * 128 + ks * 32 + lk];
  }

  float4 ev[4], xi[4], xj[4];
  int siP, diP;   // prefetched indices for the NEXT tile to be gathered

  // ---- staging helper (regs -> bf16 LDS + LN stats) ----
  auto stage = [&](int q) {
    float sum = 0.f, sq = 0.f;
#pragma unroll
    for (int i = 0; i < 4; ++i) {
      float4 v = ev[i];
      sum += (v.x + v.y) + (v.z + v.w);
      sq = fmaf(v.x, v.x, sq); sq = fmaf(v.y, v.y, sq);
      sq = fmaf(v.z, v.z, sq); sq = fmaf(v.w, v.w, sq);
      ushort4 pk; pk.x = f2bf(v.x); pk.y = f2bf(v.y); pk.z = f2bf(v.z); pk.w = f2bf(v.w);
      *(ushort4*)&Abuf[q][r][256 + (tt + 8 * i) * 4] = pk;
    }
#pragma unroll
    for (int i = 0; i < 4; ++i) {
      float4 v = xi[i];
      sum += (v.x + v.y) + (v.z + v.w);
      sq = fmaf(v.x, v.x, sq); sq = fmaf(v.y, v.y, sq);
      sq = fmaf(v.z, v.z, sq); sq = fmaf(v.w, v.w, sq);
      ushort4 pk; pk.x = f2bf(v.x); pk.y = f2bf(v.y); pk.z = f2bf(v.z); pk.w = f2bf(v.w);
      *(ushort4*)&Abuf[q][r][0 + (tt + 8 * i) * 4] = pk;
    }
#pragma unroll
    for (int i = 0; i < 4; ++i) {
      float4 v = xj[i];
      sum += (v.x + v.y) + (v.z + v.w);
      sq = fmaf(v.x, v.x, sq); sq = fmaf(v.y, v.y, sq);
      sq = fmaf(v.z, v.z, sq); sq = fmaf(v.w, v.w, sq);
      ushort4 pk; pk.x = f2bf(v.x); pk.y = f2bf(v.y); pk.z = f2bf(v.z); pk.w = f2bf(v.w);
      *(ushort4*)&Abuf[q][r][128 + (tt + 8 * i) * 4] = pk;
    }
    sum += __shfl_xor(sum, 1); sum += __shfl_xor(sum, 2); sum += __shfl_xor(sum, 4);
    sq  += __shfl_xor(sq, 1);  sq  += __shfl_xor(sq, 2);  sq  += __shfl_xor(sq, 4);
    const float mu = sum * (1.f / 384.f);
    const float var = fmaf(-mu, mu, sq * (1.f / 384.f));
    const float rstd = rsqrtf(var + 1e-5f);
    if (tt == 0) { muS[q][r] = mu; rsS[q][r] = rstd; }
  };

  auto gather = [&](int tl) {  // issue 12 float4 loads for tile tl (uses siP/diP)
    const size_t g = (size_t)tl * BM + r;
    const float4* __restrict__ pe = (const float4*)(eptr + g * 128);
    const float4* __restrict__ pi = (const float4*)(node_feat + (size_t)siP * 128);
    const float4* __restrict__ pj = (const float4*)(node_feat + (size_t)diP * 128);
#pragma unroll
    for (int i = 0; i < 4; ++i) ev[i] = pe[tt + 8 * i];
#pragma unroll
    for (int i = 0; i < 4; ++i) xi[i] = pi[tt + 8 * i];
#pragma unroll
    for (int i = 0; i < 4; ++i) xj[i] = pj[tt + 8 * i];
  };

  // ---- prologue: tile0 gathered+staged; tile1 gather in flight ----
  int tile = blockIdx.x;
  {
    const size_t g0 = (size_t)tile * BM + r;
    siP = esrc[g0]; diP = edst[g0];
    gather(tile);
  }
  int tnext = tile + GRIDSZ;
  if (tnext < NTILES) {
    const size_t g1 = (size_t)tnext * BM + r;
    siP = esrc[g1]; diP = edst[g1];
  }
  stage(0);
  if (tnext < NTILES) {
    gather(tnext);
    const int t3 = tnext + GRIDSZ;
    if (t3 < NTILES) {
      const size_t g3 = (size_t)t3 * BM + r;
      siP = esrc[g3]; diP = edst[g3];
    }
  }
  __syncthreads();

  int p = 0;
  for (;;) {
    // ---------- GEMM1 (swapped; zero global loads) ----------
    // D: col(lane&15)=edge mf*16+lr, row((lane>>4)*4+j)=feature n0+nf*16+lkrow*4+j
    f32x4 acc[2][2];
#pragma unroll
    for (int mf = 0; mf < 2; ++mf)
#pragma unroll
      for (int nf = 0; nf < 2; ++nf)
        acc[mf][nf] = (f32x4){0.f, 0.f, 0.f, 0.f};
#pragma unroll
    for (int ks = 0; ks < 12; ++ks) {
      short8 af0 = *(const short8*)&Abuf[p][lr][ks * 32 + lk];
      short8 af1 = *(const short8*)&Abuf[p][16 + lr][ks * 32 + lk];
      acc[0][0] = __builtin_amdgcn_mfma_f32_16x16x32_bf16(B1[0][ks], af0, acc[0][0], 0, 0, 0);
      acc[0][1] = __builtin_amdgcn_mfma_f32_16x16x32_bf16(B1[1][ks], af0, acc[0][1], 0, 0, 0);
      acc[1][0] = __builtin_amdgcn_mfma_f32_16x16x32_bf16(B1[0][ks], af1, acc[1][0], 0, 0, 0);
      acc[1][1] = __builtin_amdgcn_mfma_f32_16x16x32_bf16(B1[1][ks], af1, acc[1][1], 0, 0, 0);
    }
    __syncthreads();   // all waves done reading buf[p] x-sections

    // epi1: folded LN + bias + LeakyReLU -> h1 (one ushort4 write per mf,nf)
#pragma unroll
    for (int mf = 0; mf < 2; ++mf) {
      const int m = mf * 16 + lr;          // edge
      const float mu = muS[p][m];
      const float rs = rsS[p][m];
#pragma unroll
      for (int nf = 0; nf < 2; ++nf) {
        float h0 = fmaf(rs, acc[mf][nf][0] - mu * Gq[nf].x, C1q[nf].x);
        float h1 = fmaf(rs, acc[mf][nf][1] - mu * Gq[nf].y, C1q[nf].y);
        float h2 = fmaf(rs, acc[mf][nf][2] - mu * Gq[nf].z, C1q[nf].z);
        float h3 = fmaf(rs, acc[mf][nf][3] - mu * Gq[nf].w, C1q[nf].w);
        h0 = (h0 >= 0.f) ? h0 : 0.01f * h0;
        h1 = (h1 >= 0.f) ? h1 : 0.01f * h1;
        h2 = (h2 >= 0.f) ? h2 : 0.01f * h2;
        h3 = (h3 >= 0.f) ? h3 : 0.01f * h3;
        ushort4 pk; pk.x = f2bf(h0); pk.y = f2bf(h1); pk.z = f2bf(h2); pk.w = f2bf(h3);
        *(ushort4*)&Abuf[p][m][n0 + nf * 16 + lkrow * 4] = pk;
      }
    }
    __syncthreads();

    // ---------- GEMM2 (swapped; zero global loads) ----------
    f32x4 acc2[2][2];
#pragma unroll
    for (int mf = 0; mf < 2; ++mf)
#pragma unroll
      for (int nf = 0; nf < 2; ++nf)
        acc2[mf][nf] = (f32x4){0.f, 0.f, 0.f, 0.f};
#pragma unroll
    for (int ks = 0; ks < 4; ++ks) {
      short8 h0 = *(const short8*)&Abuf[p][lr][ks * 32 + lk];
      short8 h1 = *(const short8*)&Abuf[p][16 + lr][ks * 32 + lk];
      acc2[0][0] = __builtin_amdgcn_mfma_f32_16x16x32_bf16(B2[0][ks], h0, acc2[0][0], 0, 0, 0);
      acc2[0][1] = __builtin_amdgcn_mfma_f32_16x16x32_bf16(B2[1][ks], h0, acc2[0][1], 0, 0, 0);
      acc2[1][0] = __builtin_amdgcn_mfma_f32_16x16x32_bf16(B2[0][ks], h1, acc2[1][0], 0, 0, 0);
      acc2[1][1] = __builtin_amdgcn_mfma_f32_16x16x32_bf16(B2[1][ks], h1, acc2[1][1], 0, 0, 0);
    }

    // epi2: out = e(bf16, LDS) + h2 + b2  (float4 stores)
    const size_t base = (size_t)tile * BM * 128;
#pragma unroll
    for (int mf = 0; mf < 2; ++mf) {
      const int m = mf * 16 + lr;
#pragma unroll
      for (int nf = 0; nf < 2; ++nf) {
        const int nb = n0 + nf * 16 + lkrow * 4;
        ushort4 e4 = *(const ushort4*)&Abuf[p][m][256 + nb];
        float4 o;
        o.x = bf2f(e4.x) + acc2[mf][nf][0] + b2q[nf].x;
        o.y = bf2f(e4.y) + acc2[mf][nf][1] + b2q[nf].y;
        o.z = bf2f(e4.z) + acc2[mf][nf][2] + b2q[nf].z;
        o.w = bf2f(e4.w) + acc2[mf][nf][3] + b2q[nf].w;
        *(float4*)&out[base + (size_t)m * 128 + nb] = o;
      }
    }

    if (tnext >= NTILES) break;

    // stage tnext's regs -> buf[p^1] (gathers were issued a full iter ago)
    stage(p ^ 1);

    // issue gathers for t3 = tnext+GRIDSZ, prefetch idx for t4
    const int t3 = tnext + GRIDSZ;
    if (t3 < NTILES) {
      gather(t3);
      const int t4 = t3 + GRIDSZ;
      if (t4 < NTILES) {
        const size_t g4 = (size_t)t4 * BM + r;
        siP = esrc[g4]; diP = edst[g4];
      }
    }
    __syncthreads();
    p ^= 1;
    tile = tnext;
    tnext = t3;
  }
}

extern "C" void kernel_launch(void* const* d_in, const int* in_sizes, int n_in,
                              void* d_out, int out_size, void* d_ws, size_t ws_size,
                              hipStream_t stream) {
  const float* node_feat = (const float*)d_in[0];
  const int* esrc        = (const int*)d_in[1];
  const int* edst        = (const int*)d_in[2];
  const float* e         = (const float*)d_in[3];
  const float* gamma     = (const float*)d_in[4];
  const float* beta      = (const float*)d_in[5];
  const float* W1        = (const float*)d_in[6];
  const float* b1        = (const float*)d_in[7];
  const float* W2        = (const float*)d_in[8];
  const float* b2        = (const float*)d_in[9];
  float* out = (float*)d_out;

  unsigned short* Wgt = (unsigned short*)d_ws;        // 128*384 bf16
  unsigned short* W2t = Wgt + 128 * 384;              // 128*128 bf16
  float* G  = (float*)(W2t + 128 * 128);
  float* C1 = G + 128;

  prep_w<<<192, 256, 0, stream>>>(W1, gamma, W2, Wgt, W2t);
  prep_gc<<<1, 128, 0, stream>>>(W1, gamma, beta, b1, G, C1);

  edge_fused<<<GRIDSZ, 256, 0, stream>>>(node_feat, esrc, edst, e,
                                         Wgt, W2t, G, C1, b2, out);
}

// Round 10
// 273.360 us; speedup vs baseline: 1.6987x; 1.2798x over previous
//
#include <hip/hip_runtime.h>
#include <hip/hip_bf16.h>

typedef __attribute__((ext_vector_type(8))) short short8;
typedef __attribute__((ext_vector_type(4))) float f32x4;

#define NEDGES 800000
#define BM 32
#define NTILES (NEDGES / BM)   // 25000
#define CAT 384
#define APAD 8                 // stride 196 dwords == 4 (mod 32): b128 frag reads conflict-free
#define STRIDE (CAT + APAD)
#define GRIDSZ 1024            // 4 persistent blocks per CU (4 x 25.4KB LDS, VGPR 128 -> 4 waves/SIMD)

__device__ __forceinline__ unsigned short f2bf(float f) {
  union { float f; unsigned u; } v; v.f = f;
  unsigned r = v.u + 0x7fffu + ((v.u >> 16) & 1u);
  return (unsigned short)(r >> 16);
}

__device__ __forceinline__ float bf2f(unsigned short u) {
  union { unsigned u; float f; } v; v.u = ((unsigned)u) << 16;
  return v.f;
}

// ---------------- prep kernels ----------------

__global__ void prep_w(const float* __restrict__ W1, const float* __restrict__ gamma,
                       const float* __restrict__ W2,
                       unsigned short* __restrict__ Wgt, unsigned short* __restrict__ W2t) {
  int idx = blockIdx.x * 256 + threadIdx.x;
  if (idx < 128 * 384) {
    int n = idx / 384, k = idx % 384;
    Wgt[idx] = f2bf(gamma[k] * W1[k * 128 + n]);
  }
  if (idx < 128 * 128) {
    int n = idx / 128, k = idx % 128;
    W2t[idx] = f2bf(W2[k * 128 + n]);
  }
}

__global__ void prep_gc(const float* __restrict__ W1, const float* __restrict__ gamma,
                        const float* __restrict__ beta, const float* __restrict__ b1,
                        float* __restrict__ G, float* __restrict__ C1) {
  int n = threadIdx.x;  // 128 threads
  float g = 0.f, b = 0.f;
  for (int k = 0; k < 384; ++k) {
    float w = W1[k * 128 + n];
    g = fmaf(gamma[k], w, g);
    b = fmaf(beta[k], w, b);
  }
  G[n] = g;
  C1[n] = b + b1[n];
}

// ---------------- fused persistent pipelined kernel ----------------
// SINGLE-buffer LDS (25.4KB) -> 4 persistent blocks/CU (16 waves/CU).
// Next tile's gather data lives in REGISTERS (ev/xi/xj), issued one full
// iteration ahead; indices two ahead. Weights register-resident (B1 48 +
// B2 16 VGPR): zero global loads inside GEMM phases so the in-flight
// gathers never get drained by a waitcnt (vmcnt in-order).
// Swapped MFMA operands in BOTH GEMMs (D: col=edge, row=feature):
// epi1 = 4x ds_write_b64 (2-way, free at stride 196), epi2 = float4 stores.
// NOTE (R6/R8 lesson): keep __launch_bounds__(256,2). Tighter caps make the
// compiler rematerialize weights as in-loop global loads (FETCH >> 573MB).
// NOTE (R9 lesson): APAD must keep stride == 4 (mod 32) dwords; windows of
// the b128 frag reads then tile the 32 banks exactly.
__global__ __launch_bounds__(256, 2) void edge_fused(
    const float* __restrict__ node_feat,
    const int* __restrict__ esrc,
    const int* __restrict__ edst,
    const float* __restrict__ eptr,
    const unsigned short* __restrict__ Wgt,
    const unsigned short* __restrict__ W2t,
    const float* __restrict__ Gv,
    const float* __restrict__ C1v,
    const float* __restrict__ b2v,
    float* __restrict__ out) {
  __shared__ unsigned short Abuf[BM][STRIDE];   // 32 x 392 x 2B = 25088 B
  __shared__ float muS[BM];
  __shared__ float rsS[BM];

  const int tid = threadIdx.x;
  const int r  = tid >> 3;      // gather row 0..31
  const int tt = tid & 7;       // 8 threads per row
  const int l = tid & 63;
  const int w = tid >> 6;       // wave 0..3 owns n-cols [32w,32w+32)
  const int lr = l & 15;
  const int lkrow = l >> 4;
  const int lk = lkrow * 8;
  const int n0 = w * 32;

  // ---- loop-invariant weights & constants -> registers ----
  short8 B1[2][12];   // GEMM1 A-frags (swapped): Wg[feature n0+nf*16+lr][k]
  short8 B2[2][4];    // GEMM2 A-frags (swapped): W2[feature][k]
  float4 Gq[2], C1q[2], b2q[2];
#pragma unroll
  for (int nf = 0; nf < 2; ++nf) {
    const int n = n0 + nf * 16 + lr;
    const int nb = n0 + nf * 16 + lkrow * 4;
    Gq[nf]  = *(const float4*)&Gv[nb];
    C1q[nf] = *(const float4*)&C1v[nb];
    b2q[nf] = *(const float4*)&b2v[nb];
#pragma unroll
    for (int ks = 0; ks < 12; ++ks)
      B1[nf][ks] = *(const short8*)&Wgt[(size_t)n * CAT + ks * 32 + lk];
#pragma unroll
    for (int ks = 0; ks < 4; ++ks)
      B2[nf][ks] = *(const short8*)&W2t[(size_t)n * 128 + ks * 32 + lk];
  }

  float4 ev[4], xi[4], xj[4];
  int siP, diP;   // prefetched indices for the NEXT tile to be gathered

  // ---- staging helper (regs -> bf16 LDS + LN stats) ----
  auto stage = [&]() {
    float sum = 0.f, sq = 0.f;
#pragma unroll
    for (int i = 0; i < 4; ++i) {
      float4 v = ev[i];
      sum += (v.x + v.y) + (v.z + v.w);
      sq = fmaf(v.x, v.x, sq); sq = fmaf(v.y, v.y, sq);
      sq = fmaf(v.z, v.z, sq); sq = fmaf(v.w, v.w, sq);
      ushort4 pk; pk.x = f2bf(v.x); pk.y = f2bf(v.y); pk.z = f2bf(v.z); pk.w = f2bf(v.w);
      *(ushort4*)&Abuf[r][256 + (tt + 8 * i) * 4] = pk;
    }
#pragma unroll
    for (int i = 0; i < 4; ++i) {
      float4 v = xi[i];
      sum += (v.x + v.y) + (v.z + v.w);
      sq = fmaf(v.x, v.x, sq); sq = fmaf(v.y, v.y, sq);
      sq = fmaf(v.z, v.z, sq); sq = fmaf(v.w, v.w, sq);
      ushort4 pk; pk.x = f2bf(v.x); pk.y = f2bf(v.y); pk.z = f2bf(v.z); pk.w = f2bf(v.w);
      *(ushort4*)&Abuf[r][0 + (tt + 8 * i) * 4] = pk;
    }
#pragma unroll
    for (int i = 0; i < 4; ++i) {
      float4 v = xj[i];
      sum += (v.x + v.y) + (v.z + v.w);
      sq = fmaf(v.x, v.x, sq); sq = fmaf(v.y, v.y, sq);
      sq = fmaf(v.z, v.z, sq); sq = fmaf(v.w, v.w, sq);
      ushort4 pk; pk.x = f2bf(v.x); pk.y = f2bf(v.y); pk.z = f2bf(v.z); pk.w = f2bf(v.w);
      *(ushort4*)&Abuf[r][128 + (tt + 8 * i) * 4] = pk;
    }
    sum += __shfl_xor(sum, 1); sum += __shfl_xor(sum, 2); sum += __shfl_xor(sum, 4);
    sq  += __shfl_xor(sq, 1);  sq  += __shfl_xor(sq, 2);  sq  += __shfl_xor(sq, 4);
    const float mu = sum * (1.f / 384.f);
    const float var = fmaf(-mu, mu, sq * (1.f / 384.f));
    const float rstd = rsqrtf(var + 1e-5f);
    if (tt == 0) { muS[r] = mu; rsS[r] = rstd; }
  };

  auto gather = [&](int tl) {  // issue 12 float4 loads for tile tl (uses siP/diP)
    const size_t g = (size_t)tl * BM + r;
    const float4* __restrict__ pe = (const float4*)(eptr + g * 128);
    const float4* __restrict__ pi = (const float4*)(node_feat + (size_t)siP * 128);
    const float4* __restrict__ pj = (const float4*)(node_feat + (size_t)diP * 128);
#pragma unroll
    for (int i = 0; i < 4; ++i) ev[i] = pe[tt + 8 * i];
#pragma unroll
    for (int i = 0; i < 4; ++i) xi[i] = pi[tt + 8 * i];
#pragma unroll
    for (int i = 0; i < 4; ++i) xj[i] = pj[tt + 8 * i];
  };

  // ---- prologue: tile0 gathered+staged; tile1 gather in flight ----
  int tile = blockIdx.x;
  {
    const size_t g0 = (size_t)tile * BM + r;
    siP = esrc[g0]; diP = edst[g0];
    gather(tile);
  }
  int tnext = tile + GRIDSZ;
  if (tnext < NTILES) {
    const size_t g1 = (size_t)tnext * BM + r;
    siP = esrc[g1]; diP = edst[g1];
  }
  stage();
  if (tnext < NTILES) {
    gather(tnext);
    const int t3 = tnext + GRIDSZ;
    if (t3 < NTILES) {
      const size_t g3 = (size_t)t3 * BM + r;
      siP = esrc[g3]; diP = edst[g3];
    }
  }
  __syncthreads();

  for (;;) {
    // ---------- GEMM1 (swapped; zero global loads) ----------
    f32x4 acc[2][2];
#pragma unroll
    for (int mf = 0; mf < 2; ++mf)
#pragma unroll
      for (int nf = 0; nf < 2; ++nf)
        acc[mf][nf] = (f32x4){0.f, 0.f, 0.f, 0.f};
#pragma unroll
    for (int ks = 0; ks < 12; ++ks) {
      short8 af0 = *(const short8*)&Abuf[lr][ks * 32 + lk];
      short8 af1 = *(const short8*)&Abuf[16 + lr][ks * 32 + lk];
      acc[0][0] = __builtin_amdgcn_mfma_f32_16x16x32_bf16(B1[0][ks], af0, acc[0][0], 0, 0, 0);
      acc[0][1] = __builtin_amdgcn_mfma_f32_16x16x32_bf16(B1[1][ks], af0, acc[0][1], 0, 0, 0);
      acc[1][0] = __builtin_amdgcn_mfma_f32_16x16x32_bf16(B1[0][ks], af1, acc[1][0], 0, 0, 0);
      acc[1][1] = __builtin_amdgcn_mfma_f32_16x16x32_bf16(B1[1][ks], af1, acc[1][1], 0, 0, 0);
    }
    __syncthreads();   // GEMM1 reads of cols 0..127 done (epi1 will overwrite)

    // epi1: folded LN + bias + LeakyReLU -> h1 (one ushort4 write per mf,nf)
#pragma unroll
    for (int mf = 0; mf < 2; ++mf) {
      const int m = mf * 16 + lr;          // edge (D col = lane&15)
      const float mu = muS[m];
      const float rs = rsS[m];
#pragma unroll
      for (int nf = 0; nf < 2; ++nf) {
        float h0 = fmaf(rs, acc[mf][nf][0] - mu * Gq[nf].x, C1q[nf].x);
        float h1 = fmaf(rs, acc[mf][nf][1] - mu * Gq[nf].y, C1q[nf].y);
        float h2 = fmaf(rs, acc[mf][nf][2] - mu * Gq[nf].z, C1q[nf].z);
        float h3 = fmaf(rs, acc[mf][nf][3] - mu * Gq[nf].w, C1q[nf].w);
        h0 = (h0 >= 0.f) ? h0 : 0.01f * h0;
        h1 = (h1 >= 0.f) ? h1 : 0.01f * h1;
        h2 = (h2 >= 0.f) ? h2 : 0.01f * h2;
        h3 = (h3 >= 0.f) ? h3 : 0.01f * h3;
        ushort4 pk; pk.x = f2bf(h0); pk.y = f2bf(h1); pk.z = f2bf(h2); pk.w = f2bf(h3);
        *(ushort4*)&Abuf[m][n0 + nf * 16 + lkrow * 4] = pk;
      }
    }
    __syncthreads();   // h1 visible to all waves

    // ---------- GEMM2 (swapped; zero global loads) + epi2 ----------
    f32x4 acc2[2][2];
#pragma unroll
    for (int mf = 0; mf < 2; ++mf)
#pragma unroll
      for (int nf = 0; nf < 2; ++nf)
        acc2[mf][nf] = (f32x4){0.f, 0.f, 0.f, 0.f};
#pragma unroll
    for (int ks = 0; ks < 4; ++ks) {
      short8 h0 = *(const short8*)&Abuf[lr][ks * 32 + lk];
      short8 h1 = *(const short8*)&Abuf[16 + lr][ks * 32 + lk];
      acc2[0][0] = __builtin_amdgcn_mfma_f32_16x16x32_bf16(B2[0][ks], h0, acc2[0][0], 0, 0, 0);
      acc2[0][1] = __builtin_amdgcn_mfma_f32_16x16x32_bf16(B2[1][ks], h0, acc2[0][1], 0, 0, 0);
      acc2[1][0] = __builtin_amdgcn_mfma_f32_16x16x32_bf16(B2[0][ks], h1, acc2[1][0], 0, 0, 0);
      acc2[1][1] = __builtin_amdgcn_mfma_f32_16x16x32_bf16(B2[1][ks], h1, acc2[1][1], 0, 0, 0);
    }

    // epi2: out = e(bf16, LDS) + h2 + b2  (float4 stores)
    const size_t base = (size_t)tile * BM * 128;
#pragma unroll
    for (int mf = 0; mf < 2; ++mf) {
      const int m = mf * 16 + lr;
#pragma unroll
      for (int nf = 0; nf < 2; ++nf) {
        const int nb = n0 + nf * 16 + lkrow * 4;
        ushort4 e4 = *(const ushort4*)&Abuf[m][256 + nb];
        float4 o;
        o.x = bf2f(e4.x) + acc2[mf][nf][0] + b2q[nf].x;
        o.y = bf2f(e4.y) + acc2[mf][nf][1] + b2q[nf].y;
        o.z = bf2f(e4.z) + acc2[mf][nf][2] + b2q[nf].z;
        o.w = bf2f(e4.w) + acc2[mf][nf][3] + b2q[nf].w;
        *(float4*)&out[base + (size_t)m * 128 + nb] = o;
      }
    }

    if (tnext >= NTILES) break;

    __syncthreads();   // all LDS reads (h1 frags + e residual) done

    // stage tnext's regs -> LDS (gathers were issued a full iter ago)
    stage();

    // issue gathers for t3 = tnext+GRIDSZ, prefetch idx for t4
    const int t3 = tnext + GRIDSZ;
    if (t3 < NTILES) {
      gather(t3);
      const int t4 = t3 + GRIDSZ;
      if (t4 < NTILES) {
        const size_t g4 = (size_t)t4 * BM + r;
        siP = esrc[g4]; diP = edst[g4];
      }
    }
    __syncthreads();   // staged tile visible
    tile = tnext;
    tnext = t3;
  }
}

extern "C" void kernel_launch(void* const* d_in, const int* in_sizes, int n_in,
                              void* d_out, int out_size, void* d_ws, size_t ws_size,
                              hipStream_t stream) {
  const float* node_feat = (const float*)d_in[0];
  const int* esrc        = (const int*)d_in[1];
  const int* edst        = (const int*)d_in[2];
  const float* e         = (const float*)d_in[3];
  const float* gamma     = (const float*)d_in[4];
  const float* beta      = (const float*)d_in[5];
  const float* W1        = (const float*)d_in[6];
  const float* b1        = (const float*)d_in[7];
  const float* W2        = (const float*)d_in[8];
  const float* b2        = (const float*)d_in[9];
  float* out = (float*)d_out;

  unsigned short* Wgt = (unsigned short*)d_ws;        // 128*384 bf16
  unsigned short* W2t = Wgt + 128 * 384;              // 128*128 bf16
  float* G  = (float*)(W2t + 128 * 128);
  float* C1 = G + 128;

  prep_w<<<192, 256, 0, stream>>>(W1, gamma, W2, Wgt, W2t);
  prep_gc<<<1, 128, 0, stream>>>(W1, gamma, beta, b1, G, C1);

  edge_fused<<<GRIDSZ, 256, 0, stream>>>(node_feat, esrc, edst, e,
                                         Wgt, W2t, G, C1, b2, out);
}

// Round 11
// 269.220 us; speedup vs baseline: 1.7248x; 1.0154x over previous
//
#include <hip/hip_runtime.h>
#include <hip/hip_bf16.h>

typedef __attribute__((ext_vector_type(8))) short short8;
typedef __attribute__((ext_vector_type(4))) float f32x4;

#define NEDGES 800000
#define BM 32
#define NTILES (NEDGES / BM)   // 25000
#define CAT 384
#define APAD 8                 // stride 196 dw == 4 (mod 32): conflict-free b128 frag reads
#define STRIDE (CAT + APAD)
#define HPAD 8                 // Hbuf stride 68 dw == 4 (mod 32): conflict-free
#define HSTRIDE (128 + HPAD)
#define GRIDSZ 512

// hardware bf16 convert (RNE) -- compiler packs pairs into v_cvt_pk_bf16_f32
__device__ __forceinline__ unsigned short f2bf(float f) {
  union { __hip_bfloat16 h; unsigned short u; } v;
  v.h = __float2bfloat16(f);
  return v.u;
}

__device__ __forceinline__ float bf2f(unsigned short u) {
  union { unsigned u; float f; } v; v.u = ((unsigned)u) << 16;
  return v.f;
}

// ---------------- prep kernels ----------------

__global__ void prep_w(const float* __restrict__ W1, const float* __restrict__ gamma,
                       const float* __restrict__ W2,
                       unsigned short* __restrict__ Wgt, unsigned short* __restrict__ W2t) {
  int idx = blockIdx.x * 256 + threadIdx.x;
  if (idx < 128 * 384) {
    int n = idx / 384, k = idx % 384;
    Wgt[idx] = f2bf(gamma[k] * W1[k * 128 + n]);
  }
  if (idx < 128 * 128) {
    int n = idx / 128, k = idx % 128;
    W2t[idx] = f2bf(W2[k * 128 + n]);
  }
}

__global__ void prep_gc(const float* __restrict__ W1, const float* __restrict__ gamma,
                        const float* __restrict__ beta, const float* __restrict__ b1,
                        float* __restrict__ G, float* __restrict__ C1) {
  int n = threadIdx.x;  // 128 threads
  float g = 0.f, b = 0.f;
  for (int k = 0; k < 384; ++k) {
    float w = W1[k * 128 + n];
    g = fmaf(gamma[k], w, g);
    b = fmaf(beta[k], w, b);
  }
  G[n] = g;
  C1[n] = b + b1[n];
}

// ---------------- fused persistent pipelined kernel ----------------
// R10 base (persistent, single Abuf, reg-resident weights, swapped GEMMs)
// R11: (1) f2bf via hardware cvt (compiler packs to v_cvt_pk_bf16_f32),
// (2) separate Hbuf kills the GEMM1-overwrite barrier (4 -> 3 barriers),
// (3) gathers issued mid-iteration (after GEMM1) -- invariant preserved:
// no global LOADS inside either GEMM phase, so the in-flight gathers are
// never drained early (vmcnt in-order; stores issued after don't matter).
// NOTE (R6/R8): keep __launch_bounds__(256,2); tighter caps => weight
// rematerialization (signature: FETCH >> 573MB).
// NOTE (R10): occupancy is capped at 2 waves/SIMD by UNIFIED reg file
// (128 VGPR + ~128 AGPR-parked weights); don't chase blocks/CU.
__global__ __launch_bounds__(256, 2) void edge_fused(
    const float* __restrict__ node_feat,
    const int* __restrict__ esrc,
    const int* __restrict__ edst,
    const float* __restrict__ eptr,
    const unsigned short* __restrict__ Wgt,
    const unsigned short* __restrict__ W2t,
    const float* __restrict__ Gv,
    const float* __restrict__ C1v,
    const float* __restrict__ b2v,
    float* __restrict__ out) {
  __shared__ unsigned short Abuf[BM][STRIDE];    // 32 x 392 x 2B = 25088 B
  __shared__ unsigned short Hbuf[BM][HSTRIDE];   // 32 x 136 x 2B =  8704 B
  __shared__ float muS[BM];
  __shared__ float rsS[BM];

  const int tid = threadIdx.x;
  const int r  = tid >> 3;      // gather row 0..31
  const int tt = tid & 7;       // 8 threads per row
  const int l = tid & 63;
  const int w = tid >> 6;       // wave 0..3 owns n-cols [32w,32w+32)
  const int lr = l & 15;
  const int lkrow = l >> 4;
  const int lk = lkrow * 8;
  const int n0 = w * 32;

  // ---- loop-invariant weights & constants -> registers ----
  short8 B1[2][12];   // GEMM1 A-frags (swapped): Wg[feature n0+nf*16+lr][k]
  short8 B2[2][4];    // GEMM2 A-frags (swapped): W2[feature][k]
  float4 Gq[2], C1q[2], b2q[2];
#pragma unroll
  for (int nf = 0; nf < 2; ++nf) {
    const int n = n0 + nf * 16 + lr;
    const int nb = n0 + nf * 16 + lkrow * 4;
    Gq[nf]  = *(const float4*)&Gv[nb];
    C1q[nf] = *(const float4*)&C1v[nb];
    b2q[nf] = *(const float4*)&b2v[nb];
#pragma unroll
    for (int ks = 0; ks < 12; ++ks)
      B1[nf][ks] = *(const short8*)&Wgt[(size_t)n * CAT + ks * 32 + lk];
#pragma unroll
    for (int ks = 0; ks < 4; ++ks)
      B2[nf][ks] = *(const short8*)&W2t[(size_t)n * 128 + ks * 32 + lk];
  }

  float4 ev[4], xi[4], xj[4];
  int siP, diP;   // prefetched indices for the NEXT tile to be gathered

  // ---- staging helper (regs -> bf16 LDS + LN stats) ----
  auto stage = [&]() {
    float sum = 0.f, sq = 0.f;
#pragma unroll
    for (int i = 0; i < 4; ++i) {
      float4 v = ev[i];
      sum += (v.x + v.y) + (v.z + v.w);
      sq = fmaf(v.x, v.x, sq); sq = fmaf(v.y, v.y, sq);
      sq = fmaf(v.z, v.z, sq); sq = fmaf(v.w, v.w, sq);
      ushort4 pk; pk.x = f2bf(v.x); pk.y = f2bf(v.y); pk.z = f2bf(v.z); pk.w = f2bf(v.w);
      *(ushort4*)&Abuf[r][256 + (tt + 8 * i) * 4] = pk;
    }
#pragma unroll
    for (int i = 0; i < 4; ++i) {
      float4 v = xi[i];
      sum += (v.x + v.y) + (v.z + v.w);
      sq = fmaf(v.x, v.x, sq); sq = fmaf(v.y, v.y, sq);
      sq = fmaf(v.z, v.z, sq); sq = fmaf(v.w, v.w, sq);
      ushort4 pk; pk.x = f2bf(v.x); pk.y = f2bf(v.y); pk.z = f2bf(v.z); pk.w = f2bf(v.w);
      *(ushort4*)&Abuf[r][0 + (tt + 8 * i) * 4] = pk;
    }
#pragma unroll
    for (int i = 0; i < 4; ++i) {
      float4 v = xj[i];
      sum += (v.x + v.y) + (v.z + v.w);
      sq = fmaf(v.x, v.x, sq); sq = fmaf(v.y, v.y, sq);
      sq = fmaf(v.z, v.z, sq); sq = fmaf(v.w, v.w, sq);
      ushort4 pk; pk.x = f2bf(v.x); pk.y = f2bf(v.y); pk.z = f2bf(v.z); pk.w = f2bf(v.w);
      *(ushort4*)&Abuf[r][128 + (tt + 8 * i) * 4] = pk;
    }
    sum += __shfl_xor(sum, 1); sum += __shfl_xor(sum, 2); sum += __shfl_xor(sum, 4);
    sq  += __shfl_xor(sq, 1);  sq  += __shfl_xor(sq, 2);  sq  += __shfl_xor(sq, 4);
    const float mu = sum * (1.f / 384.f);
    const float var = fmaf(-mu, mu, sq * (1.f / 384.f));
    const float rstd = rsqrtf(var + 1e-5f);
    if (tt == 0) { muS[r] = mu; rsS[r] = rstd; }
  };

  auto gather = [&](int tl) {  // issue 12 float4 loads for tile tl (uses siP/diP)
    const size_t g = (size_t)tl * BM + r;
    const float4* __restrict__ pe = (const float4*)(eptr + g * 128);
    const float4* __restrict__ pi = (const float4*)(node_feat + (size_t)siP * 128);
    const float4* __restrict__ pj = (const float4*)(node_feat + (size_t)diP * 128);
#pragma unroll
    for (int i = 0; i < 4; ++i) ev[i] = pe[tt + 8 * i];
#pragma unroll
    for (int i = 0; i < 4; ++i) xi[i] = pi[tt + 8 * i];
#pragma unroll
    for (int i = 0; i < 4; ++i) xj[i] = pj[tt + 8 * i];
  };

  // ---- prologue: gather+stage tile0; idx for tile1 ready ----
  int tile = blockIdx.x;
  {
    const size_t g0 = (size_t)tile * BM + r;
    siP = esrc[g0]; diP = edst[g0];
    gather(tile);
  }
  int tnext = tile + GRIDSZ;
  if (tnext < NTILES) {
    const size_t g1 = (size_t)tnext * BM + r;
    siP = esrc[g1]; diP = edst[g1];
  }
  stage();
  __syncthreads();

  for (;;) {
    // ---------- GEMM1 (swapped; zero global loads) ----------
    f32x4 acc[2][2];
#pragma unroll
    for (int mf = 0; mf < 2; ++mf)
#pragma unroll
      for (int nf = 0; nf < 2; ++nf)
        acc[mf][nf] = (f32x4){0.f, 0.f, 0.f, 0.f};
#pragma unroll
    for (int ks = 0; ks < 12; ++ks) {
      short8 af0 = *(const short8*)&Abuf[lr][ks * 32 + lk];
      short8 af1 = *(const short8*)&Abuf[16 + lr][ks * 32 + lk];
      acc[0][0] = __builtin_amdgcn_mfma_f32_16x16x32_bf16(B1[0][ks], af0, acc[0][0], 0, 0, 0);
      acc[0][1] = __builtin_amdgcn_mfma_f32_16x16x32_bf16(B1[1][ks], af0, acc[0][1], 0, 0, 0);
      acc[1][0] = __builtin_amdgcn_mfma_f32_16x16x32_bf16(B1[0][ks], af1, acc[1][0], 0, 0, 0);
      acc[1][1] = __builtin_amdgcn_mfma_f32_16x16x32_bf16(B1[1][ks], af1, acc[1][1], 0, 0, 0);
    }

    // ---- mid-iteration gather issue for tile tnext (hidden under epi1+GEMM2) ----
    if (tnext < NTILES) {
      gather(tnext);
      const int t3 = tnext + GRIDSZ;
      if (t3 < NTILES) {
        const size_t g3 = (size_t)t3 * BM + r;
        siP = esrc[g3]; diP = edst[g3];
      }
    }

    // epi1: folded LN + bias + LeakyReLU -> Hbuf (ushort4 per mf,nf)
#pragma unroll
    for (int mf = 0; mf < 2; ++mf) {
      const int m = mf * 16 + lr;          // edge (D col = lane&15)
      const float mu = muS[m];
      const float rs = rsS[m];
#pragma unroll
      for (int nf = 0; nf < 2; ++nf) {
        float h0 = fmaf(rs, acc[mf][nf][0] - mu * Gq[nf].x, C1q[nf].x);
        float h1 = fmaf(rs, acc[mf][nf][1] - mu * Gq[nf].y, C1q[nf].y);
        float h2 = fmaf(rs, acc[mf][nf][2] - mu * Gq[nf].z, C1q[nf].z);
        float h3 = fmaf(rs, acc[mf][nf][3] - mu * Gq[nf].w, C1q[nf].w);
        h0 = (h0 >= 0.f) ? h0 : 0.01f * h0;
        h1 = (h1 >= 0.f) ? h1 : 0.01f * h1;
        h2 = (h2 >= 0.f) ? h2 : 0.01f * h2;
        h3 = (h3 >= 0.f) ? h3 : 0.01f * h3;
        ushort4 pk; pk.x = f2bf(h0); pk.y = f2bf(h1); pk.z = f2bf(h2); pk.w = f2bf(h3);
        *(ushort4*)&Hbuf[m][n0 + nf * 16 + lkrow * 4] = pk;
      }
    }
    __syncthreads();   // Hbuf visible (GEMM1 Abuf reads also all complete)

    // ---------- GEMM2 (swapped; zero global loads) + epi2 ----------
    f32x4 acc2[2][2];
#pragma unroll
    for (int mf = 0; mf < 2; ++mf)
#pragma unroll
      for (int nf = 0; nf < 2; ++nf)
        acc2[mf][nf] = (f32x4){0.f, 0.f, 0.f, 0.f};
#pragma unroll
    for (int ks = 0; ks < 4; ++ks) {
      short8 h0 = *(const short8*)&Hbuf[lr][ks * 32 + lk];
      short8 h1 = *(const short8*)&Hbuf[16 + lr][ks * 32 + lk];
      acc2[0][0] = __builtin_amdgcn_mfma_f32_16x16x32_bf16(B2[0][ks], h0, acc2[0][0], 0, 0, 0);
      acc2[0][1] = __builtin_amdgcn_mfma_f32_16x16x32_bf16(B2[1][ks], h0, acc2[0][1], 0, 0, 0);
      acc2[1][0] = __builtin_amdgcn_mfma_f32_16x16x32_bf16(B2[0][ks], h1, acc2[1][0], 0, 0, 0);
      acc2[1][1] = __builtin_amdgcn_mfma_f32_16x16x32_bf16(B2[1][ks], h1, acc2[1][1], 0, 0, 0);
    }

    // epi2: out = e(bf16, LDS) + h2 + b2  (float4 stores)
    const size_t base = (size_t)tile * BM * 128;
#pragma unroll
    for (int mf = 0; mf < 2; ++mf) {
      const int m = mf * 16 + lr;
#pragma unroll
      for (int nf = 0; nf < 2; ++nf) {
        const int nb = n0 + nf * 16 + lkrow * 4;
        ushort4 e4 = *(const ushort4*)&Abuf[m][256 + nb];
        float4 o;
        o.x = bf2f(e4.x) + acc2[mf][nf][0] + b2q[nf].x;
        o.y = bf2f(e4.y) + acc2[mf][nf][1] + b2q[nf].y;
        o.z = bf2f(e4.z) + acc2[mf][nf][2] + b2q[nf].z;
        o.w = bf2f(e4.w) + acc2[mf][nf][3] + b2q[nf].w;
        *(float4*)&out[base + (size_t)m * 128 + nb] = o;
      }
    }

    if (tnext >= NTILES) break;

    __syncthreads();   // all Abuf reads (e residual) done; safe to overwrite

    // stage tnext's regs -> Abuf (gathers issued mid-iteration, now landed)
    stage();
    __syncthreads();   // staged tile visible

    tile = tnext;
    tnext = tile + GRIDSZ;
  }
}

extern "C" void kernel_launch(void* const* d_in, const int* in_sizes, int n_in,
                              void* d_out, int out_size, void* d_ws, size_t ws_size,
                              hipStream_t stream) {
  const float* node_feat = (const float*)d_in[0];
  const int* esrc        = (const int*)d_in[1];
  const int* edst        = (const int*)d_in[2];
  const float* e         = (const float*)d_in[3];
  const float* gamma     = (const float*)d_in[4];
  const float* beta      = (const float*)d_in[5];
  const float* W1        = (const float*)d_in[6];
  const float* b1        = (const float*)d_in[7];
  const float* W2        = (const float*)d_in[8];
  const float* b2        = (const float*)d_in[9];
  float* out = (float*)d_out;

  unsigned short* Wgt = (unsigned short*)d_ws;        // 128*384 bf16
  unsigned short* W2t = Wgt + 128 * 384;              // 128*128 bf16
  float* G  = (float*)(W2t + 128 * 128);
  float* C1 = G + 128;

  prep_w<<<192, 256, 0, stream>>>(W1, gamma, W2, Wgt, W2t);
  prep_gc<<<1, 128, 0, stream>>>(W1, gamma, beta, b1, G, C1);

  edge_fused<<<GRIDSZ, 256, 0, stream>>>(node_feat, esrc, edst, e,
                                         Wgt, W2t, G, C1, b2, out);
}

// Round 12
// 266.819 us; speedup vs baseline: 1.7404x; 1.0090x over previous
//
#include <hip/hip_runtime.h>
#include <hip/hip_bf16.h>

typedef __attribute__((ext_vector_type(8))) short short8;
typedef __attribute__((ext_vector_type(4))) float f32x4;

#define NEDGES 800000
#define BM 32
#define NTILES (NEDGES / BM)   // 25000
#define CAT 384
#define APAD 8                 // stride 196 dw == 4 (mod 32): conflict-free b128 frag reads
#define STRIDE (CAT + APAD)
#define HPAD 8                 // Hbuf stride 68 dw == 4 (mod 32)
#define HSTRIDE (128 + HPAD)
#define GRIDSZ 512

// hardware bf16 convert (RNE) -- compiler packs pairs into v_cvt_pk_bf16_f32
__device__ __forceinline__ unsigned short f2bf(float f) {
  union { __hip_bfloat16 h; unsigned short u; } v;
  v.h = __float2bfloat16(f);
  return v.u;
}

__device__ __forceinline__ float bf2f(unsigned short u) {
  union { unsigned u; float f; } v; v.u = ((unsigned)u) << 16;
  return v.f;
}

// ---------------- prep kernels ----------------

__global__ void prep_w(const float* __restrict__ W1, const float* __restrict__ gamma,
                       const float* __restrict__ W2,
                       unsigned short* __restrict__ Wgt, unsigned short* __restrict__ W2t) {
  int idx = blockIdx.x * 256 + threadIdx.x;
  if (idx < 128 * 384) {
    int n = idx / 384, k = idx % 384;
    Wgt[idx] = f2bf(gamma[k] * W1[k * 128 + n]);
  }
  if (idx < 128 * 128) {
    int n = idx / 128, k = idx % 128;
    W2t[idx] = f2bf(W2[k * 128 + n]);
  }
}

__global__ void prep_gc(const float* __restrict__ W1, const float* __restrict__ gamma,
                        const float* __restrict__ beta, const float* __restrict__ b1,
                        float* __restrict__ G, float* __restrict__ C1) {
  int n = threadIdx.x;  // 128 threads
  float g = 0.f, b = 0.f;
  for (int k = 0; k < 384; ++k) {
    float w = W1[k * 128 + n];
    g = fmaf(gamma[k], w, g);
    b = fmaf(beta[k], w, b);
  }
  G[n] = g;
  C1[n] = b + b1[n];
}

// ---------------- fused persistent pipelined kernel ----------------
// R11 base. R12: (1) gathers for tile t+1 issued BEFORE GEMM1 (zero global
// ops inside the GEMMs -> loads stay in flight across the whole iteration,
// maximizing HBM-request duty cycle); compiler memory fence pins the issue
// point. (2) s_setprio(1) around MFMA clusters (two independent blocks/CU
// at different phases -> scheduler favors the MFMA wave).
// NOTE (R6/R8): keep __launch_bounds__(256,2); tighter caps => weight
// rematerialization (signature: FETCH >> 573MB).
// NOTE (R10/R11): occupancy is hard-capped at 2 waves/SIMD by the unified
// VGPR+AGPR file (128 arch + ~128 parked weights); don't chase blocks/CU.
__global__ __launch_bounds__(256, 2) void edge_fused(
    const float* __restrict__ node_feat,
    const int* __restrict__ esrc,
    const int* __restrict__ edst,
    const float* __restrict__ eptr,
    const unsigned short* __restrict__ Wgt,
    const unsigned short* __restrict__ W2t,
    const float* __restrict__ Gv,
    const float* __restrict__ C1v,
    const float* __restrict__ b2v,
    float* __restrict__ out) {
  __shared__ unsigned short Abuf[BM][STRIDE];    // 32 x 392 x 2B = 25088 B
  __shared__ unsigned short Hbuf[BM][HSTRIDE];   // 32 x 136 x 2B =  8704 B
  __shared__ float muS[BM];
  __shared__ float rsS[BM];

  const int tid = threadIdx.x;
  const int r  = tid >> 3;      // gather row 0..31
  const int tt = tid & 7;       // 8 threads per row
  const int l = tid & 63;
  const int w = tid >> 6;       // wave 0..3 owns n-cols [32w,32w+32)
  const int lr = l & 15;
  const int lkrow = l >> 4;
  const int lk = lkrow * 8;
  const int n0 = w * 32;

  // ---- loop-invariant weights & constants -> registers ----
  short8 B1[2][12];   // GEMM1 A-frags (swapped): Wg[feature n0+nf*16+lr][k]
  short8 B2[2][4];    // GEMM2 A-frags (swapped): W2[feature][k]
  float4 Gq[2], C1q[2], b2q[2];
#pragma unroll
  for (int nf = 0; nf < 2; ++nf) {
    const int n = n0 + nf * 16 + lr;
    const int nb = n0 + nf * 16 + lkrow * 4;
    Gq[nf]  = *(const float4*)&Gv[nb];
    C1q[nf] = *(const float4*)&C1v[nb];
    b2q[nf] = *(const float4*)&b2v[nb];
#pragma unroll
    for (int ks = 0; ks < 12; ++ks)
      B1[nf][ks] = *(const short8*)&Wgt[(size_t)n * CAT + ks * 32 + lk];
#pragma unroll
    for (int ks = 0; ks < 4; ++ks)
      B2[nf][ks] = *(const short8*)&W2t[(size_t)n * 128 + ks * 32 + lk];
  }

  float4 ev[4], xi[4], xj[4];
  int siP, diP;   // prefetched indices for the NEXT tile to be gathered

  // ---- staging helper (regs -> bf16 LDS + LN stats) ----
  auto stage = [&]() {
    float sum = 0.f, sq = 0.f;
#pragma unroll
    for (int i = 0; i < 4; ++i) {
      float4 v = ev[i];
      sum += (v.x + v.y) + (v.z + v.w);
      sq = fmaf(v.x, v.x, sq); sq = fmaf(v.y, v.y, sq);
      sq = fmaf(v.z, v.z, sq); sq = fmaf(v.w, v.w, sq);
      ushort4 pk; pk.x = f2bf(v.x); pk.y = f2bf(v.y); pk.z = f2bf(v.z); pk.w = f2bf(v.w);
      *(ushort4*)&Abuf[r][256 + (tt + 8 * i) * 4] = pk;
    }
#pragma unroll
    for (int i = 0; i < 4; ++i) {
      float4 v = xi[i];
      sum += (v.x + v.y) + (v.z + v.w);
      sq = fmaf(v.x, v.x, sq); sq = fmaf(v.y, v.y, sq);
      sq = fmaf(v.z, v.z, sq); sq = fmaf(v.w, v.w, sq);
      ushort4 pk; pk.x = f2bf(v.x); pk.y = f2bf(v.y); pk.z = f2bf(v.z); pk.w = f2bf(v.w);
      *(ushort4*)&Abuf[r][0 + (tt + 8 * i) * 4] = pk;
    }
#pragma unroll
    for (int i = 0; i < 4; ++i) {
      float4 v = xj[i];
      sum += (v.x + v.y) + (v.z + v.w);
      sq = fmaf(v.x, v.x, sq); sq = fmaf(v.y, v.y, sq);
      sq = fmaf(v.z, v.z, sq); sq = fmaf(v.w, v.w, sq);
      ushort4 pk; pk.x = f2bf(v.x); pk.y = f2bf(v.y); pk.z = f2bf(v.z); pk.w = f2bf(v.w);
      *(ushort4*)&Abuf[r][128 + (tt + 8 * i) * 4] = pk;
    }
    sum += __shfl_xor(sum, 1); sum += __shfl_xor(sum, 2); sum += __shfl_xor(sum, 4);
    sq  += __shfl_xor(sq, 1);  sq  += __shfl_xor(sq, 2);  sq  += __shfl_xor(sq, 4);
    const float mu = sum * (1.f / 384.f);
    const float var = fmaf(-mu, mu, sq * (1.f / 384.f));
    const float rstd = rsqrtf(var + 1e-5f);
    if (tt == 0) { muS[r] = mu; rsS[r] = rstd; }
  };

  auto gather = [&](int tl) {  // issue 12 float4 loads for tile tl (uses siP/diP)
    const size_t g = (size_t)tl * BM + r;
    const float4* __restrict__ pe = (const float4*)(eptr + g * 128);
    const float4* __restrict__ pi = (const float4*)(node_feat + (size_t)siP * 128);
    const float4* __restrict__ pj = (const float4*)(node_feat + (size_t)diP * 128);
#pragma unroll
    for (int i = 0; i < 4; ++i) ev[i] = pe[tt + 8 * i];
#pragma unroll
    for (int i = 0; i < 4; ++i) xi[i] = pi[tt + 8 * i];
#pragma unroll
    for (int i = 0; i < 4; ++i) xj[i] = pj[tt + 8 * i];
  };

  // ---- prologue: gather+stage tile0; idx for tile1 ready ----
  int tile = blockIdx.x;
  {
    const size_t g0 = (size_t)tile * BM + r;
    siP = esrc[g0]; diP = edst[g0];
    gather(tile);
  }
  int tnext = tile + GRIDSZ;
  if (tnext < NTILES) {
    const size_t g1 = (size_t)tnext * BM + r;
    siP = esrc[g1]; diP = edst[g1];
  }
  stage();
  __syncthreads();

  for (;;) {
    // ---- issue gathers for tnext FIRST: they stay in flight across the
    // entire iteration (GEMMs contain zero global memory operations) ----
    if (tnext < NTILES) {
      gather(tnext);
      const int t3 = tnext + GRIDSZ;
      if (t3 < NTILES) {
        const size_t g3 = (size_t)t3 * BM + r;
        siP = esrc[g3]; diP = edst[g3];
      }
    }
    asm volatile("" ::: "memory");   // pin the issue point (no sinking)

    // ---------- GEMM1 (swapped; zero global loads) ----------
    f32x4 acc[2][2];
#pragma unroll
    for (int mf = 0; mf < 2; ++mf)
#pragma unroll
      for (int nf = 0; nf < 2; ++nf)
        acc[mf][nf] = (f32x4){0.f, 0.f, 0.f, 0.f};
    __builtin_amdgcn_s_setprio(1);
#pragma unroll
    for (int ks = 0; ks < 12; ++ks) {
      short8 af0 = *(const short8*)&Abuf[lr][ks * 32 + lk];
      short8 af1 = *(const short8*)&Abuf[16 + lr][ks * 32 + lk];
      acc[0][0] = __builtin_amdgcn_mfma_f32_16x16x32_bf16(B1[0][ks], af0, acc[0][0], 0, 0, 0);
      acc[0][1] = __builtin_amdgcn_mfma_f32_16x16x32_bf16(B1[1][ks], af0, acc[0][1], 0, 0, 0);
      acc[1][0] = __builtin_amdgcn_mfma_f32_16x16x32_bf16(B1[0][ks], af1, acc[1][0], 0, 0, 0);
      acc[1][1] = __builtin_amdgcn_mfma_f32_16x16x32_bf16(B1[1][ks], af1, acc[1][1], 0, 0, 0);
    }
    __builtin_amdgcn_s_setprio(0);

    // epi1: folded LN + bias + LeakyReLU -> Hbuf (ushort4 per mf,nf)
#pragma unroll
    for (int mf = 0; mf < 2; ++mf) {
      const int m = mf * 16 + lr;          // edge (D col = lane&15)
      const float mu = muS[m];
      const float rs = rsS[m];
#pragma unroll
      for (int nf = 0; nf < 2; ++nf) {
        float h0 = fmaf(rs, acc[mf][nf][0] - mu * Gq[nf].x, C1q[nf].x);
        float h1 = fmaf(rs, acc[mf][nf][1] - mu * Gq[nf].y, C1q[nf].y);
        float h2 = fmaf(rs, acc[mf][nf][2] - mu * Gq[nf].z, C1q[nf].z);
        float h3 = fmaf(rs, acc[mf][nf][3] - mu * Gq[nf].w, C1q[nf].w);
        h0 = (h0 >= 0.f) ? h0 : 0.01f * h0;
        h1 = (h1 >= 0.f) ? h1 : 0.01f * h1;
        h2 = (h2 >= 0.f) ? h2 : 0.01f * h2;
        h3 = (h3 >= 0.f) ? h3 : 0.01f * h3;
        ushort4 pk; pk.x = f2bf(h0); pk.y = f2bf(h1); pk.z = f2bf(h2); pk.w = f2bf(h3);
        *(ushort4*)&Hbuf[m][n0 + nf * 16 + lkrow * 4] = pk;
      }
    }
    __syncthreads();   // Hbuf visible (GEMM1 Abuf reads also all complete)

    // ---------- GEMM2 (swapped; zero global loads) + epi2 ----------
    f32x4 acc2[2][2];
#pragma unroll
    for (int mf = 0; mf < 2; ++mf)
#pragma unroll
      for (int nf = 0; nf < 2; ++nf)
        acc2[mf][nf] = (f32x4){0.f, 0.f, 0.f, 0.f};
    __builtin_amdgcn_s_setprio(1);
#pragma unroll
    for (int ks = 0; ks < 4; ++ks) {
      short8 h0 = *(const short8*)&Hbuf[lr][ks * 32 + lk];
      short8 h1 = *(const short8*)&Hbuf[16 + lr][ks * 32 + lk];
      acc2[0][0] = __builtin_amdgcn_mfma_f32_16x16x32_bf16(B2[0][ks], h0, acc2[0][0], 0, 0, 0);
      acc2[0][1] = __builtin_amdgcn_mfma_f32_16x16x32_bf16(B2[1][ks], h0, acc2[0][1], 0, 0, 0);
      acc2[1][0] = __builtin_amdgcn_mfma_f32_16x16x32_bf16(B2[0][ks], h1, acc2[1][0], 0, 0, 0);
      acc2[1][1] = __builtin_amdgcn_mfma_f32_16x16x32_bf16(B2[1][ks], h1, acc2[1][1], 0, 0, 0);
    }
    __builtin_amdgcn_s_setprio(0);

    // epi2: out = e(bf16, LDS) + h2 + b2  (float4 stores)
    const size_t base = (size_t)tile * BM * 128;
#pragma unroll
    for (int mf = 0; mf < 2; ++mf) {
      const int m = mf * 16 + lr;
#pragma unroll
      for (int nf = 0; nf < 2; ++nf) {
        const int nb = n0 + nf * 16 + lkrow * 4;
        ushort4 e4 = *(const ushort4*)&Abuf[m][256 + nb];
        float4 o;
        o.x = bf2f(e4.x) + acc2[mf][nf][0] + b2q[nf].x;
        o.y = bf2f(e4.y) + acc2[mf][nf][1] + b2q[nf].y;
        o.z = bf2f(e4.z) + acc2[mf][nf][2] + b2q[nf].z;
        o.w = bf2f(e4.w) + acc2[mf][nf][3] + b2q[nf].w;
        *(float4*)&out[base + (size_t)m * 128 + nb] = o;
      }
    }

    if (tnext >= NTILES) break;

    __syncthreads();   // all Abuf reads (e residual) done; safe to overwrite

    // stage tnext's regs -> Abuf (gathers have had the full iteration to land)
    stage();
    __syncthreads();   // staged tile visible

    tile = tnext;
    tnext = tile + GRIDSZ;
  }
}

extern "C" void kernel_launch(void* const* d_in, const int* in_sizes, int n_in,
                              void* d_out, int out_size, void* d_ws, size_t ws_size,
                              hipStream_t stream) {
  const float* node_feat = (const float*)d_in[0];
  const int* esrc        = (const int*)d_in[1];
  const int* edst        = (const int*)d_in[2];
  const float* e         = (const float*)d_in[3];
  const float* gamma     = (const float*)d_in[4];
  const float* beta      = (const float*)d_in[5];
  const float* W1        = (const float*)d_in[6];
  const float* b1        = (const float*)d_in[7];
  const float* W2        = (const float*)d_in[8];
  const float* b2        = (const float*)d_in[9];
  float* out = (float*)d_out;

  unsigned short* Wgt = (unsigned short*)d_ws;        // 128*384 bf16
  unsigned short* W2t = Wgt + 128 * 384;              // 128*128 bf16
  float* G  = (float*)(W2t + 128 * 128);
  float* C1 = G + 128;

  prep_w<<<192, 256, 0, stream>>>(W1, gamma, W2, Wgt, W2t);
  prep_gc<<<1, 128, 0, stream>>>(W1, gamma, beta, b1, G, C1);

  edge_fused<<<GRIDSZ, 256, 0, stream>>>(node_feat, esrc, edst, e,
                                         Wgt, W2t, G, C1, b2, out);
}